// Round 13
// baseline (2158.786 us; speedup 1.0000x reference)
//
#include <hip/hip_runtime.h>
#include <hip/hip_fp16.h>

#define N_ROWS 65536
#define D_COLS 1024
#define M_ROWS 32768
#define QROWS  16384   // rows per scatter pass (64KB f32 LDS, 2 blocks/CU)
#define REPS   4       // DIAGNOSTIC: amplify each kernel above the harness fills

using u32 = unsigned int;
using u16 = unsigned short;
typedef float f32x4 __attribute__((ext_vector_type(4)));   // native vecs for nontemporal
typedef int   i32x4 __attribute__((ext_vector_type(4)));

// ---- ws[0] = 0 (abs-max accumulator) ----
__global__ void init_ws_k(u32* ws) {
    if (threadIdx.x == 0 && blockIdx.x == 0) ws[0] = 0u;
}

// ---- 64x64-tile transpose: idx[M,D]->idxT[D,M] (u16), upd[M,D]*scl[j] -> updT[D,M] (fp16) ----
__global__ __launch_bounds__(256) void t_idx_upd_k(const int* __restrict__ idx,
                                                   const float* __restrict__ upd,
                                                   const float* __restrict__ scl,
                                                   u16* __restrict__ idxT,
                                                   __half* __restrict__ updT) {
    __shared__ u32   sidx[64][65];
    __shared__ float supd[64][65];
    const int j0 = (int)(blockIdx.x & 15) * 64;   // 16 j-tiles
    const int i0 = (int)(blockIdx.x >> 4) * 64;   // 512 i-tiles
    const int t = threadIdx.x;

    for (int rep = 0; rep < REPS; ++rep) {
        {
            const int rr = t >> 2, c4 = t & 3;
            const int*   ip = idx + (size_t)(i0 + rr) * D_COLS + j0;
            const float* up = upd + (size_t)(i0 + rr) * D_COLS + j0;
            #pragma unroll
            for (int cq = 0; cq < 4; ++cq) {
                const int jc = cq * 16 + c4 * 4;
                const i32x4 iv = __builtin_nontemporal_load((const i32x4*)(ip + jc));
                const f32x4 uv = __builtin_nontemporal_load((const f32x4*)(up + jc));
                sidx[rr][jc] = (u32)iv.x; sidx[rr][jc+1] = (u32)iv.y;
                sidx[rr][jc+2] = (u32)iv.z; sidx[rr][jc+3] = (u32)iv.w;
                supd[rr][jc] = uv.x; supd[rr][jc+1] = uv.y;
                supd[rr][jc+2] = uv.z; supd[rr][jc+3] = uv.w;
            }
        }
        __syncthreads();
        {
            const int jj = t >> 2, seg = t & 3;
            const __half hs = __float2half(scl[j0 + jj]);   // exact fp16 scale
            u32 wi[8], wh[8];
            #pragma unroll
            for (int p = 0; p < 8; ++p) {
                const int r = seg * 16 + 2 * p;
                const u32 a = sidx[r][jj] & 0xffffu, b = sidx[r + 1][jj] & 0xffffu;
                wi[p] = a | (b << 16);
                const __half2 h2 = __halves2half2(__hmul(__float2half(supd[r][jj]), hs),
                                                  __hmul(__float2half(supd[r + 1][jj]), hs));
                wh[p] = *reinterpret_cast<const u32*>(&h2);
            }
            u16* di = idxT + (size_t)(j0 + jj) * M_ROWS + i0 + seg * 16;
            __half* dh = updT + (size_t)(j0 + jj) * M_ROWS + i0 + seg * 16;
            ((uint4*)di)[0] = uint4{wi[0], wi[1], wi[2], wi[3]};
            ((uint4*)di)[1] = uint4{wi[4], wi[5], wi[6], wi[7]};
            ((uint4*)dh)[0] = uint4{wh[0], wh[1], wh[2], wh[3]};
            ((uint4*)dh)[1] = uint4{wh[4], wh[5], wh[6], wh[7]};
        }
        __syncthreads();
        asm volatile("" ::: "memory");   // block cross-rep DSE/CSE
    }
}

// ---- per (column j, quarter h): zero 64KB LDS, scan column, LDS atomics, fp16 write ----
__global__ __launch_bounds__(1024) void scatter_q_k(const u16* __restrict__ idxT,
                                                    const __half* __restrict__ updT,
                                                    __half* __restrict__ sumT) {
    __shared__ float acc[QROWS];                  // 64 KB
    const int bid = (blockIdx.x & 7) * 512 + (blockIdx.x >> 3);  // bijective, 4096%8==0
    const int j = bid >> 2;                       // column 0..1023
    const int h = bid & 3;                        // row quarter
    const int tid = threadIdx.x;

    for (int rep = 0; rep < REPS; ++rep) {
        float4* acc4 = (float4*)acc;
        for (int t = tid; t < QROWS / 4; t += 1024) acc4[t] = float4{0.f, 0.f, 0.f, 0.f};

        const int4* ip4 = (const int4*)(idxT + (size_t)j * M_ROWS);  // 4096 int4
        const int4* up4 = (const int4*)(updT + (size_t)j * M_ROWS);
        __syncthreads();

        #pragma unroll
        for (int k = 0; k < 4; ++k) {
            const int t = k * 1024 + tid;
            const int4 iv = ip4[t];
            const int4 uv = up4[t];
            const u32 iw[4] = {(u32)iv.x, (u32)iv.y, (u32)iv.z, (u32)iv.w};
            const u32 uw[4] = {(u32)uv.x, (u32)uv.y, (u32)uv.z, (u32)uv.w};
            #pragma unroll
            for (int e = 0; e < 4; ++e) {
                const int r0 = iw[e] & 0xffff, r1 = iw[e] >> 16;
                const __half2 h2 = *reinterpret_cast<const __half2*>(&uw[e]);
                if ((r0 >> 14) == h) atomicAdd(&acc[r0 & (QROWS - 1)], __half2float(__low2half(h2)));
                if ((r1 >> 14) == h) atomicAdd(&acc[r1 & (QROWS - 1)], __half2float(__high2half(h2)));
            }
        }
        __syncthreads();

        __half2* dst = (__half2*)(sumT + (size_t)j * N_ROWS + h * QROWS);
        for (int t = tid; t < QROWS / 2; t += 1024)
            dst[t] = __floats2half2_rn(acc[2 * t], acc[2 * t + 1]);
        __syncthreads();
        asm volatile("" ::: "memory");
    }
}

// ---- 64x64 tiles: out = var*s + sumT^T; fused abs-max ----
__global__ __launch_bounds__(256) void finalize_k(const int* __restrict__ var,
                                                  const __half* __restrict__ sumT,
                                                  const float* __restrict__ var_scale,
                                                  float* __restrict__ outf,
                                                  u32* __restrict__ ws) {
    __shared__ float sm[64][65];
    __shared__ float wmax[4];
    const int r0 = (int)(blockIdx.x >> 4) * 64;   // 1024 row-tiles
    const int j0 = (int)(blockIdx.x & 15) * 64;   // 16 col-tiles
    const int tid = threadIdx.x;
    const float s = var_scale[0];

    for (int rep = 0; rep < REPS; ++rep) {
        {
            const int jj = tid >> 2, seg = tid & 3;
            const __half* colp = sumT + (size_t)(j0 + jj) * N_ROWS + r0 + seg * 16;
            #pragma unroll
            for (int q = 0; q < 2; ++q) {
                const uint4 w = ((const uint4*)colp)[q];
                const u32 wv[4] = {w.x, w.y, w.z, w.w};
                #pragma unroll
                for (int i = 0; i < 4; ++i) {
                    const __half2 hh = *reinterpret_cast<const __half2*>(&wv[i]);
                    const float2 f = __half22float2(hh);
                    const int rr = seg * 16 + q * 8 + i * 2;
                    sm[rr][jj] = f.x;
                    sm[rr + 1][jj] = f.y;
                }
            }
        }
        __syncthreads();

        float m = 0.f;
        #pragma unroll
        for (int k = 0; k < 4; ++k) {
            const int l = k * 256 + tid;              // 0..1023 int4 units
            const int rr = l >> 4, c4 = l & 15;
            const i32x4 v = __builtin_nontemporal_load(
                (const i32x4*)(var + (size_t)(r0 + rr) * D_COLS + j0) + c4);
            float4 o;
            o.x = (float)v.x * s + sm[rr][c4 * 4 + 0];
            o.y = (float)v.y * s + sm[rr][c4 * 4 + 1];
            o.z = (float)v.z * s + sm[rr][c4 * 4 + 2];
            o.w = (float)v.w * s + sm[rr][c4 * 4 + 3];
            ((float4*)(outf + (size_t)(r0 + rr) * D_COLS + j0))[c4] = o;
            m = fmaxf(m, fmaxf(fmaxf(fabsf(o.x), fabsf(o.y)),
                               fmaxf(fabsf(o.z), fabsf(o.w))));
        }
        for (int off = 32; off; off >>= 1) m = fmaxf(m, __shfl_xor(m, off));
        if ((tid & 63) == 0) wmax[tid >> 6] = m;
        __syncthreads();
        if (tid == 0) {
            m = fmaxf(fmaxf(wmax[0], wmax[1]), fmaxf(wmax[2], wmax[3]));
            atomicMax(ws, __float_as_uint(m));
        }
        __syncthreads();
        asm volatile("" ::: "memory");
    }
}

// ---- y = clip(rint(out * 127/max), -128, 127) stored as f32; write scale ----
__global__ __launch_bounds__(256) void quant_k(const float4* __restrict__ outf4,
                                               f32x4* __restrict__ y4,
                                               const u32* __restrict__ ws,
                                               float* __restrict__ scale_out, int n4) {
    const float mx = __uint_as_float(ws[0]);
    const float inv = 127.0f / mx;
    int gid = blockIdx.x * 256 + threadIdx.x;
    if (gid == 0) scale_out[0] = mx / 127.0f;
    const int stride = gridDim.x * 256;
    for (int rep = 0; rep < REPS; ++rep) {
        for (int i = gid; i < n4; i += stride) {
            float4 v = outf4[i];
            f32x4 o;
            o.x = fminf(fmaxf(rintf(v.x * inv), -128.f), 127.f);
            o.y = fminf(fmaxf(rintf(v.y * inv), -128.f), 127.f);
            o.z = fminf(fmaxf(rintf(v.z * inv), -128.f), 127.f);
            o.w = fminf(fmaxf(rintf(v.w * inv), -128.f), 127.f);
            __builtin_nontemporal_store(o, &y4[i]);   // y never re-read
        }
        asm volatile("" ::: "memory");
    }
}

extern "C" void kernel_launch(void* const* d_in, const int* in_sizes, int n_in,
                              void* d_out, int out_size, void* d_ws, size_t ws_size,
                              hipStream_t stream) {
    const int*   var       = (const int*)d_in[0];     // int8 transported as int32
    const float* var_scale = (const float*)d_in[1];
    const int*   idx       = (const int*)d_in[2];
    const float* upd       = (const float*)d_in[3];   // fp16 transported as f32
    const float* scl       = (const float*)d_in[4];   // fp16 transported as f32

    float* y    = (float*)d_out;                      // y (f32) [N*D]
    float* outf = y + (size_t)N_ROWS * D_COLS;        // out (f32) [N*D]
    float* scale_out = y + 2 * (size_t)N_ROWS * D_COLS;

    // scratch packed into the (not-yet-written) y region: exactly 256 MB
    char* scratch = (char*)y;
    u16*    idxT = (u16*)scratch;                               // 64 MB
    __half* updT = (__half*)(scratch + (size_t)67108864);       // 64 MB
    __half* sumT = (__half*)(scratch + (size_t)134217728);      // 128 MB
    u32* ws = (u32*)d_ws;

    const int n4 = N_ROWS * D_COLS / 4;

    init_ws_k<<<1, 64, 0, stream>>>(ws);
    t_idx_upd_k<<<8192, 256, 0, stream>>>(idx, upd, scl, idxT, updT);
    scatter_q_k<<<4096, 1024, 0, stream>>>(idxT, updT, sumT);
    finalize_k<<<16384, 256, 0, stream>>>(var, sumT, var_scale, outf, ws);
    quant_k<<<4096, 256, 0, stream>>>((const float4*)outf, (f32x4*)y, ws, scale_out, n4);
}

// Round 14
// 569.177 us; speedup vs baseline: 3.7928x; 3.7928x over previous
//
#include <hip/hip_runtime.h>
#include <hip/hip_fp16.h>

#define N_ROWS 65536
#define D_COLS 1024
#define M_ROWS 32768
#define QROWS  16384   // rows per scatter pass (64KB f32 LDS)

using u32 = unsigned int;
using u16 = unsigned short;
typedef float f32x4 __attribute__((ext_vector_type(4)));   // native vecs for nontemporal
typedef int   i32x4 __attribute__((ext_vector_type(4)));

// ---- ws[0] = 0 (abs-max accumulator) ----
__global__ void init_ws_k(u32* ws) {
    if (threadIdx.x == 0 && blockIdx.x == 0) ws[0] = 0u;
}

// ---- 64x64-tile transpose: idx[M,D]->idxT[D,M] (u16), upd[M,D]*scl[j] -> updT[D,M] (fp16)
//      i-INNER + XCD-banded order: each XCD streams its 2 column-bands sequentially,
//      so the column-major writes are DRAM-page-friendly. ----
__global__ __launch_bounds__(256) void t_idx_upd_k(const int* __restrict__ idx,
                                                   const float* __restrict__ upd,
                                                   const float* __restrict__ scl,
                                                   u16* __restrict__ idxT,
                                                   __half* __restrict__ updT) {
    __shared__ u32   sidx[64][65];
    __shared__ float supd[64][65];
    const int swz = (int)(blockIdx.x & 7) * 1024 + (int)(blockIdx.x >> 3); // 8192%8==0
    const int i0 = (swz & 511) * 64;              // i-tile INNER (512 i-tiles)
    const int j0 = (swz >> 9) * 64;               // j-tile outer (16 j-tiles)
    const int t = threadIdx.x;

    {
        const int rr = t >> 2, c4 = t & 3;
        const int*   ip = idx + (size_t)(i0 + rr) * D_COLS + j0;
        const float* up = upd + (size_t)(i0 + rr) * D_COLS + j0;
        #pragma unroll
        for (int cq = 0; cq < 4; ++cq) {
            const int jc = cq * 16 + c4 * 4;
            const i32x4 iv = __builtin_nontemporal_load((const i32x4*)(ip + jc));
            const f32x4 uv = __builtin_nontemporal_load((const f32x4*)(up + jc));
            sidx[rr][jc] = (u32)iv.x; sidx[rr][jc+1] = (u32)iv.y;
            sidx[rr][jc+2] = (u32)iv.z; sidx[rr][jc+3] = (u32)iv.w;
            supd[rr][jc] = uv.x; supd[rr][jc+1] = uv.y;
            supd[rr][jc+2] = uv.z; supd[rr][jc+3] = uv.w;
        }
    }
    __syncthreads();

    {
        const int jj = t >> 2, seg = t & 3;
        const __half hs = __float2half(scl[j0 + jj]);   // exact fp16 scale
        u32 wi[8], wh[8];
        #pragma unroll
        for (int p = 0; p < 8; ++p) {
            const int r = seg * 16 + 2 * p;
            const u32 a = sidx[r][jj] & 0xffffu, b = sidx[r + 1][jj] & 0xffffu;
            wi[p] = a | (b << 16);
            const __half2 h2 = __halves2half2(__hmul(__float2half(supd[r][jj]), hs),
                                              __hmul(__float2half(supd[r + 1][jj]), hs));
            wh[p] = *reinterpret_cast<const u32*>(&h2);
        }
        u16* di = idxT + (size_t)(j0 + jj) * M_ROWS + i0 + seg * 16;
        __half* dh = updT + (size_t)(j0 + jj) * M_ROWS + i0 + seg * 16;
        ((uint4*)di)[0] = uint4{wi[0], wi[1], wi[2], wi[3]};
        ((uint4*)di)[1] = uint4{wi[4], wi[5], wi[6], wi[7]};
        ((uint4*)dh)[0] = uint4{wh[0], wh[1], wh[2], wh[3]};
        ((uint4*)dh)[1] = uint4{wh[4], wh[5], wh[6], wh[7]};
    }
}

// ---- per (column j, quarter h): zero 64KB LDS, scan column, LDS atomics, fp16 write.
//      (near the LDS-atomic wall per R13 diagnostics — unchanged) ----
__global__ __launch_bounds__(1024) void scatter_q_k(const u16* __restrict__ idxT,
                                                    const __half* __restrict__ updT,
                                                    __half* __restrict__ sumT) {
    __shared__ float acc[QROWS];                  // 64 KB
    const int bid = (blockIdx.x & 7) * 512 + (blockIdx.x >> 3);  // bijective, 4096%8==0
    const int j = bid >> 2;                       // column 0..1023
    const int h = bid & 3;                        // row quarter
    const int tid = threadIdx.x;

    float4* acc4 = (float4*)acc;
    for (int t = tid; t < QROWS / 4; t += 1024) acc4[t] = float4{0.f, 0.f, 0.f, 0.f};

    const int4* ip4 = (const int4*)(idxT + (size_t)j * M_ROWS);  // 4096 int4
    const int4* up4 = (const int4*)(updT + (size_t)j * M_ROWS);
    __syncthreads();

    #pragma unroll
    for (int k = 0; k < 4; ++k) {
        const int t = k * 1024 + tid;
        const int4 iv = ip4[t];
        const int4 uv = up4[t];
        const u32 iw[4] = {(u32)iv.x, (u32)iv.y, (u32)iv.z, (u32)iv.w};
        const u32 uw[4] = {(u32)uv.x, (u32)uv.y, (u32)uv.z, (u32)uv.w};
        #pragma unroll
        for (int e = 0; e < 4; ++e) {
            const int r0 = iw[e] & 0xffff, r1 = iw[e] >> 16;
            const __half2 h2 = *reinterpret_cast<const __half2*>(&uw[e]);
            if ((r0 >> 14) == h) atomicAdd(&acc[r0 & (QROWS - 1)], __half2float(__low2half(h2)));
            if ((r1 >> 14) == h) atomicAdd(&acc[r1 & (QROWS - 1)], __half2float(__high2half(h2)));
        }
    }
    __syncthreads();

    __half2* dst = (__half2*)(sumT + (size_t)j * N_ROWS + h * QROWS);
    for (int t = tid; t < QROWS / 2; t += 1024)
        dst[t] = __floats2half2_rn(acc[2 * t], acc[2 * t + 1]);
}

// ---- 64x64 tiles: out = var*s + sumT^T; r-INNER + XCD-banded order so sumT's
//      column reads stream sequentially per XCD (DRAM-page-friendly); [68] pad
//      gives b128 LDS reads; fused abs-max. ----
__global__ __launch_bounds__(256) void finalize_k(const int* __restrict__ var,
                                                  const __half* __restrict__ sumT,
                                                  const float* __restrict__ var_scale,
                                                  float* __restrict__ outf,
                                                  u32* __restrict__ ws) {
    __shared__ float sm[64][68];
    __shared__ float wmax[4];
    const int swz = (int)(blockIdx.x & 7) * 2048 + (int)(blockIdx.x >> 3); // 16384%8==0
    const int r0 = (swz & 1023) * 64;             // r-tile INNER (1024 r-tiles)
    const int j0 = (swz >> 10) * 64;              // j-tile outer (16 j-tiles)
    const int tid = threadIdx.x;
    const float s = var_scale[0];

    {
        const int jj = tid >> 2, seg = tid & 3;
        const __half* colp = sumT + (size_t)(j0 + jj) * N_ROWS + r0 + seg * 16;
        #pragma unroll
        for (int q = 0; q < 2; ++q) {
            const uint4 w = ((const uint4*)colp)[q];
            const u32 wv[4] = {w.x, w.y, w.z, w.w};
            #pragma unroll
            for (int i = 0; i < 4; ++i) {
                const __half2 hh = *reinterpret_cast<const __half2*>(&wv[i]);
                const float2 f = __half22float2(hh);
                const int rr = seg * 16 + q * 8 + i * 2;
                sm[rr][jj] = f.x;
                sm[rr + 1][jj] = f.y;
            }
        }
    }
    __syncthreads();

    float m = 0.f;
    #pragma unroll
    for (int k = 0; k < 4; ++k) {
        const int l = k * 256 + tid;              // 0..1023 int4 units
        const int rr = l >> 4, c4 = l & 15;
        const i32x4 v = __builtin_nontemporal_load(
            (const i32x4*)(var + (size_t)(r0 + rr) * D_COLS + j0) + c4);
        const float4 sv = *(const float4*)&sm[rr][c4 * 4];   // b128 (rows 272B-aligned)
        float4 o;
        o.x = (float)v.x * s + sv.x;
        o.y = (float)v.y * s + sv.y;
        o.z = (float)v.z * s + sv.z;
        o.w = (float)v.w * s + sv.w;
        ((float4*)(outf + (size_t)(r0 + rr) * D_COLS + j0))[c4] = o;
        m = fmaxf(m, fmaxf(fmaxf(fabsf(o.x), fabsf(o.y)),
                           fmaxf(fabsf(o.z), fabsf(o.w))));
    }
    for (int off = 32; off; off >>= 1) m = fmaxf(m, __shfl_xor(m, off));
    if ((tid & 63) == 0) wmax[tid >> 6] = m;
    __syncthreads();
    if (tid == 0) {
        m = fmaxf(fmaxf(wmax[0], wmax[1]), fmaxf(wmax[2], wmax[3]));
        atomicMax(ws, __float_as_uint(m));
    }
}

// ---- y = clip(rint(out * 127/max), -128, 127) stored as f32; write scale ----
__global__ __launch_bounds__(256) void quant_k(const float4* __restrict__ outf4,
                                               f32x4* __restrict__ y4,
                                               const u32* __restrict__ ws,
                                               float* __restrict__ scale_out, int n4) {
    const float mx = __uint_as_float(ws[0]);
    const float inv = 127.0f / mx;
    int gid = blockIdx.x * 256 + threadIdx.x;
    if (gid == 0) scale_out[0] = mx / 127.0f;
    const int stride = gridDim.x * 256;
    for (int i = gid; i < n4; i += stride) {
        float4 v = outf4[i];
        f32x4 o;
        o.x = fminf(fmaxf(rintf(v.x * inv), -128.f), 127.f);
        o.y = fminf(fmaxf(rintf(v.y * inv), -128.f), 127.f);
        o.z = fminf(fmaxf(rintf(v.z * inv), -128.f), 127.f);
        o.w = fminf(fmaxf(rintf(v.w * inv), -128.f), 127.f);
        __builtin_nontemporal_store(o, &y4[i]);   // y never re-read
    }
}

extern "C" void kernel_launch(void* const* d_in, const int* in_sizes, int n_in,
                              void* d_out, int out_size, void* d_ws, size_t ws_size,
                              hipStream_t stream) {
    const int*   var       = (const int*)d_in[0];     // int8 transported as int32
    const float* var_scale = (const float*)d_in[1];
    const int*   idx       = (const int*)d_in[2];
    const float* upd       = (const float*)d_in[3];   // fp16 transported as f32
    const float* scl       = (const float*)d_in[4];   // fp16 transported as f32

    float* y    = (float*)d_out;                      // y (f32) [N*D]
    float* outf = y + (size_t)N_ROWS * D_COLS;        // out (f32) [N*D]
    float* scale_out = y + 2 * (size_t)N_ROWS * D_COLS;

    // scratch packed into the (not-yet-written) y region: exactly 256 MB
    char* scratch = (char*)y;
    u16*    idxT = (u16*)scratch;                               // 64 MB
    __half* updT = (__half*)(scratch + (size_t)67108864);       // 64 MB
    __half* sumT = (__half*)(scratch + (size_t)134217728);      // 128 MB
    u32* ws = (u32*)d_ws;

    const int n4 = N_ROWS * D_COLS / 4;

    init_ws_k<<<1, 64, 0, stream>>>(ws);
    t_idx_upd_k<<<8192, 256, 0, stream>>>(idx, upd, scl, idxT, updT);
    scatter_q_k<<<4096, 1024, 0, stream>>>(idxT, updT, sumT);
    finalize_k<<<16384, 256, 0, stream>>>(var, sumT, var_scale, outf, ws);
    quant_k<<<4096, 256, 0, stream>>>((const float4*)outf, (f32x4*)y, ws, scale_out, n4);
}

// Round 15
// 568.725 us; speedup vs baseline: 3.7958x; 1.0008x over previous
//
#include <hip/hip_runtime.h>
#include <hip/hip_fp16.h>

#define N_ROWS 65536
#define D_COLS 1024
#define M_ROWS 32768
#define EROWS  8192    // rows per scatter pass (32KB f32 LDS -> up to 4 blocks/CU)

using u32 = unsigned int;
using u16 = unsigned short;
typedef float f32x4 __attribute__((ext_vector_type(4)));   // native vecs for nontemporal
typedef int   i32x4 __attribute__((ext_vector_type(4)));

// ---- ws[0] = 0 (abs-max accumulator) ----
__global__ void init_ws_k(u32* ws) {
    if (threadIdx.x == 0 && blockIdx.x == 0) ws[0] = 0u;
}

// ---- 64x64-tile transpose: idx[M,D]->idxT[D,M] (u16), upd[M,D]*scl[j] -> updT[D,M] (fp16)
//      i-INNER + XCD-banded order (column-major writes stream per XCD). ----
__global__ __launch_bounds__(256) void t_idx_upd_k(const int* __restrict__ idx,
                                                   const float* __restrict__ upd,
                                                   const float* __restrict__ scl,
                                                   u16* __restrict__ idxT,
                                                   __half* __restrict__ updT) {
    __shared__ u32   sidx[64][65];
    __shared__ float supd[64][65];
    const int swz = (int)(blockIdx.x & 7) * 1024 + (int)(blockIdx.x >> 3); // 8192%8==0
    const int i0 = (swz & 511) * 64;              // i-tile INNER (512 i-tiles)
    const int j0 = (swz >> 9) * 64;               // j-tile outer (16 j-tiles)
    const int t = threadIdx.x;

    {
        const int rr = t >> 2, c4 = t & 3;
        const int*   ip = idx + (size_t)(i0 + rr) * D_COLS + j0;
        const float* up = upd + (size_t)(i0 + rr) * D_COLS + j0;
        #pragma unroll
        for (int cq = 0; cq < 4; ++cq) {
            const int jc = cq * 16 + c4 * 4;
            const i32x4 iv = __builtin_nontemporal_load((const i32x4*)(ip + jc));
            const f32x4 uv = __builtin_nontemporal_load((const f32x4*)(up + jc));
            sidx[rr][jc] = (u32)iv.x; sidx[rr][jc+1] = (u32)iv.y;
            sidx[rr][jc+2] = (u32)iv.z; sidx[rr][jc+3] = (u32)iv.w;
            supd[rr][jc] = uv.x; supd[rr][jc+1] = uv.y;
            supd[rr][jc+2] = uv.z; supd[rr][jc+3] = uv.w;
        }
    }
    __syncthreads();

    {
        const int jj = t >> 2, seg = t & 3;
        const __half hs = __float2half(scl[j0 + jj]);   // exact fp16 scale
        u32 wi[8], wh[8];
        #pragma unroll
        for (int p = 0; p < 8; ++p) {
            const int r = seg * 16 + 2 * p;
            const u32 a = sidx[r][jj] & 0xffffu, b = sidx[r + 1][jj] & 0xffffu;
            wi[p] = a | (b << 16);
            const __half2 h2 = __halves2half2(__hmul(__float2half(supd[r][jj]), hs),
                                              __hmul(__float2half(supd[r + 1][jj]), hs));
            wh[p] = *reinterpret_cast<const u32*>(&h2);
        }
        u16* di = idxT + (size_t)(j0 + jj) * M_ROWS + i0 + seg * 16;
        __half* dh = updT + (size_t)(j0 + jj) * M_ROWS + i0 + seg * 16;
        ((uint4*)di)[0] = uint4{wi[0], wi[1], wi[2], wi[3]};
        ((uint4*)di)[1] = uint4{wi[4], wi[5], wi[6], wi[7]};
        ((uint4*)dh)[0] = uint4{wh[0], wh[1], wh[2], wh[3]};
        ((uint4*)dh)[1] = uint4{wh[4], wh[5], wh[6], wh[7]};
    }
}

// ---- per (column j, eighth h): zero 32KB LDS, scan column, LDS atomics, fp16 write.
//      32KB LDS + 512 thr -> up to 4 blocks/CU so the barrier-separated phases of
//      different blocks overlap (R13-R14 showed 1-resident-block serialization). ----
__global__ __launch_bounds__(512) void scatter_e_k(const u16* __restrict__ idxT,
                                                   const __half* __restrict__ updT,
                                                   __half* __restrict__ sumT) {
    __shared__ float acc[EROWS];                  // 32 KB
    const int bid = (int)(blockIdx.x & 7) * 1024 + (int)(blockIdx.x >> 3); // 8192%8==0
    const int j = bid >> 3;                       // column 0..1023
    const int h = bid & 7;                        // row eighth (all 8 on one XCD)
    const int tid = threadIdx.x;

    float4* acc4 = (float4*)acc;
    for (int t = tid; t < EROWS / 4; t += 512) acc4[t] = float4{0.f, 0.f, 0.f, 0.f};

    const int4* ip4 = (const int4*)(idxT + (size_t)j * M_ROWS);  // 4096 int4
    const int4* up4 = (const int4*)(updT + (size_t)j * M_ROWS);
    __syncthreads();

    #pragma unroll
    for (int k = 0; k < 8; ++k) {
        const int t = k * 512 + tid;
        const int4 iv = ip4[t];
        const int4 uv = up4[t];
        const u32 iw[4] = {(u32)iv.x, (u32)iv.y, (u32)iv.z, (u32)iv.w};
        const u32 uw[4] = {(u32)uv.x, (u32)uv.y, (u32)uv.z, (u32)uv.w};
        #pragma unroll
        for (int e = 0; e < 4; ++e) {
            const int r0 = iw[e] & 0xffff, r1 = iw[e] >> 16;
            const __half2 h2 = *reinterpret_cast<const __half2*>(&uw[e]);
            if ((r0 >> 13) == h) atomicAdd(&acc[r0 & (EROWS - 1)], __half2float(__low2half(h2)));
            if ((r1 >> 13) == h) atomicAdd(&acc[r1 & (EROWS - 1)], __half2float(__high2half(h2)));
        }
    }
    __syncthreads();

    __half2* dst = (__half2*)(sumT + (size_t)j * N_ROWS + h * EROWS);
    for (int t = tid; t < EROWS / 2; t += 512)
        dst[t] = __floats2half2_rn(acc[2 * t], acc[2 * t + 1]);
}

// ---- 64x64 tiles: out = var*s + sumT^T; r-INNER + XCD-banded; fused abs-max ----
__global__ __launch_bounds__(256) void finalize_k(const int* __restrict__ var,
                                                  const __half* __restrict__ sumT,
                                                  const float* __restrict__ var_scale,
                                                  float* __restrict__ outf,
                                                  u32* __restrict__ ws) {
    __shared__ float sm[64][68];
    __shared__ float wmax[4];
    const int swz = (int)(blockIdx.x & 7) * 2048 + (int)(blockIdx.x >> 3); // 16384%8==0
    const int r0 = (swz & 1023) * 64;             // r-tile INNER (1024 r-tiles)
    const int j0 = (swz >> 10) * 64;              // j-tile outer (16 j-tiles)
    const int tid = threadIdx.x;
    const float s = var_scale[0];

    {
        const int jj = tid >> 2, seg = tid & 3;
        const __half* colp = sumT + (size_t)(j0 + jj) * N_ROWS + r0 + seg * 16;
        #pragma unroll
        for (int q = 0; q < 2; ++q) {
            const uint4 w = ((const uint4*)colp)[q];
            const u32 wv[4] = {w.x, w.y, w.z, w.w};
            #pragma unroll
            for (int i = 0; i < 4; ++i) {
                const __half2 hh = *reinterpret_cast<const __half2*>(&wv[i]);
                const float2 f = __half22float2(hh);
                const int rr = seg * 16 + q * 8 + i * 2;
                sm[rr][jj] = f.x;
                sm[rr + 1][jj] = f.y;
            }
        }
    }
    __syncthreads();

    float m = 0.f;
    #pragma unroll
    for (int k = 0; k < 4; ++k) {
        const int l = k * 256 + tid;              // 0..1023 int4 units
        const int rr = l >> 4, c4 = l & 15;
        const i32x4 v = __builtin_nontemporal_load(
            (const i32x4*)(var + (size_t)(r0 + rr) * D_COLS + j0) + c4);
        const float4 sv = *(const float4*)&sm[rr][c4 * 4];   // b128 LDS read
        float4 o;
        o.x = (float)v.x * s + sv.x;
        o.y = (float)v.y * s + sv.y;
        o.z = (float)v.z * s + sv.z;
        o.w = (float)v.w * s + sv.w;
        ((float4*)(outf + (size_t)(r0 + rr) * D_COLS + j0))[c4] = o;
        m = fmaxf(m, fmaxf(fmaxf(fabsf(o.x), fabsf(o.y)),
                           fmaxf(fabsf(o.z), fabsf(o.w))));
    }
    for (int off = 32; off; off >>= 1) m = fmaxf(m, __shfl_xor(m, off));
    if ((tid & 63) == 0) wmax[tid >> 6] = m;
    __syncthreads();
    if (tid == 0) {
        m = fmaxf(fmaxf(wmax[0], wmax[1]), fmaxf(wmax[2], wmax[3]));
        atomicMax(ws, __float_as_uint(m));
    }
}

// ---- y = clip(rint(out * 127/max), -128, 127) stored as f32; write scale ----
__global__ __launch_bounds__(256) void quant_k(const float4* __restrict__ outf4,
                                               f32x4* __restrict__ y4,
                                               const u32* __restrict__ ws,
                                               float* __restrict__ scale_out, int n4) {
    const float mx = __uint_as_float(ws[0]);
    const float inv = 127.0f / mx;
    int gid = blockIdx.x * 256 + threadIdx.x;
    if (gid == 0) scale_out[0] = mx / 127.0f;
    const int stride = gridDim.x * 256;
    for (int i = gid; i < n4; i += stride) {
        float4 v = outf4[i];
        f32x4 o;
        o.x = fminf(fmaxf(rintf(v.x * inv), -128.f), 127.f);
        o.y = fminf(fmaxf(rintf(v.y * inv), -128.f), 127.f);
        o.z = fminf(fmaxf(rintf(v.z * inv), -128.f), 127.f);
        o.w = fminf(fmaxf(rintf(v.w * inv), -128.f), 127.f);
        __builtin_nontemporal_store(o, &y4[i]);   // y never re-read
    }
}

extern "C" void kernel_launch(void* const* d_in, const int* in_sizes, int n_in,
                              void* d_out, int out_size, void* d_ws, size_t ws_size,
                              hipStream_t stream) {
    const int*   var       = (const int*)d_in[0];     // int8 transported as int32
    const float* var_scale = (const float*)d_in[1];
    const int*   idx       = (const int*)d_in[2];
    const float* upd       = (const float*)d_in[3];   // fp16 transported as f32
    const float* scl       = (const float*)d_in[4];   // fp16 transported as f32

    float* y    = (float*)d_out;                      // y (f32) [N*D]
    float* outf = y + (size_t)N_ROWS * D_COLS;        // out (f32) [N*D]
    float* scale_out = y + 2 * (size_t)N_ROWS * D_COLS;

    // scratch packed into the (not-yet-written) y region: exactly 256 MB
    char* scratch = (char*)y;
    u16*    idxT = (u16*)scratch;                               // 64 MB
    __half* updT = (__half*)(scratch + (size_t)67108864);       // 64 MB
    __half* sumT = (__half*)(scratch + (size_t)134217728);      // 128 MB
    u32* ws = (u32*)d_ws;

    const int n4 = N_ROWS * D_COLS / 4;

    init_ws_k<<<1, 64, 0, stream>>>(ws);
    t_idx_upd_k<<<8192, 256, 0, stream>>>(idx, upd, scl, idxT, updT);
    scatter_e_k<<<8192, 512, 0, stream>>>(idxT, updT, sumT);
    finalize_k<<<16384, 256, 0, stream>>>(var, sumT, var_scale, outf, ws);
    quant_k<<<4096, 256, 0, stream>>>((const float4*)outf, (f32x4*)y, ws, scale_out, n4);
}